// Round 1
// baseline (903.005 us; speedup 1.0000x reference)
//
#include <hip/hip_runtime.h>
#include <hip/hip_bf16.h>
#include <math.h>

// Problem constants (B=4, T=1024, D_MODEL=1024, H=16, D_HEAD=64)
#define SEQ_T   1024
#define DMODEL  1024
#define NHEAD   16
#define DHEAD   64
#define MROWS   4096            // B*T
#define QKV_N   3072

// ---------------------------------------------------------------------------
// Kernel 1: qkv = x @ Wqkv  (4096x1024 @ 1024x3072), fused RoPE epilogue.
// Tile 128x128, BK=8, 256 threads, 8x8 per thread. fp32 vector FMA.
// Writes q (scaled by 1/8, roped), k (roped), v into ws in (B,H,T,D) layout.
// ---------------------------------------------------------------------------
__global__ __launch_bounds__(256) void k_qkv_rope(
    const float* __restrict__ X,     // (4096, 1024)
    const float* __restrict__ W,     // (1024, 3072)
    const float* __restrict__ COS,   // (1024, 64)
    const float* __restrict__ SIN,   // (1024, 64)
    float* __restrict__ qws, float* __restrict__ kws, float* __restrict__ vws)
{
    __shared__ float As[8][128];
    __shared__ float Bs[8][128];
    const int tid = threadIdx.x;
    const int tx = tid & 15, ty = tid >> 4;
    const int M0 = blockIdx.y * 128, N0 = blockIdx.x * 128;

    float acc[8][8];
    #pragma unroll
    for (int i = 0; i < 8; i++)
        #pragma unroll
        for (int j = 0; j < 8; j++) acc[i][j] = 0.f;

    const int arow = tid >> 1, acol = (tid & 1) * 4;
    const int brow = tid >> 5, bcol = (tid & 31) * 4;
    const float* Aptr = X + (size_t)(M0 + arow) * 1024 + acol;
    const float* Bptr = W + (size_t)brow * QKV_N + N0 + bcol;

    for (int kt = 0; kt < 1024; kt += 8) {
        float4 a = *(const float4*)(Aptr + kt);
        float4 b = *(const float4*)(Bptr + (size_t)kt * QKV_N);
        __syncthreads();
        As[acol + 0][arow] = a.x; As[acol + 1][arow] = a.y;
        As[acol + 2][arow] = a.z; As[acol + 3][arow] = a.w;
        *(float4*)&Bs[brow][bcol] = b;
        __syncthreads();
        #pragma unroll
        for (int k = 0; k < 8; k++) {
            float4 a0 = *(const float4*)&As[k][ty * 4];
            float4 a1 = *(const float4*)&As[k][64 + ty * 4];
            float4 b0 = *(const float4*)&Bs[k][tx * 4];
            float4 b1 = *(const float4*)&Bs[k][64 + tx * 4];
            float am[8] = {a0.x, a0.y, a0.z, a0.w, a1.x, a1.y, a1.z, a1.w};
            float bv[8] = {b0.x, b0.y, b0.z, b0.w, b1.x, b1.y, b1.z, b1.w};
            #pragma unroll
            for (int i = 0; i < 8; i++)
                #pragma unroll
                for (int j = 0; j < 8; j++)
                    acc[i][j] = fmaf(am[i], bv[j], acc[i][j]);
        }
    }

    // Epilogue: RoPE + scatter to (B,H,T,D) q/k/v buffers.
    #pragma unroll
    for (int rg = 0; rg < 2; rg++) {
        #pragma unroll
        for (int i = 0; i < 4; i++) {
            const int m = M0 + rg * 64 + ty * 4 + i;
            const int bb = m >> 10, t = m & 1023;
            #pragma unroll
            for (int cg = 0; cg < 2; cg++) {
                const int n = N0 + cg * 64 + tx * 4;
                const int which = n >> 10;          // 0=q 1=k 2=v
                const int cin = n & 1023;
                const int h = cin >> 6, d0 = cin & 63;
                const float v0 = acc[rg * 4 + i][cg * 4 + 0];
                const float v1 = acc[rg * 4 + i][cg * 4 + 1];
                const float v2 = acc[rg * 4 + i][cg * 4 + 2];
                const float v3 = acc[rg * 4 + i][cg * 4 + 3];
                float4 o;
                if (which < 2) {
                    const float4 c = *(const float4*)&COS[t * 64 + d0];
                    const float4 s = *(const float4*)&SIN[t * 64 + d0];
                    // interleaved rotate_half: out[2i]=x[2i]c-x[2i+1]s; out[2i+1]=x[2i+1]c+x[2i]s
                    o.x = v0 * c.x - v1 * s.x;
                    o.y = v1 * c.y + v0 * s.y;
                    o.z = v2 * c.z - v3 * s.z;
                    o.w = v3 * c.w + v2 * s.w;
                    if (which == 0) {               // fold 1/sqrt(64) into q
                        o.x *= 0.125f; o.y *= 0.125f; o.z *= 0.125f; o.w *= 0.125f;
                    }
                } else {
                    o = make_float4(v0, v1, v2, v3);
                }
                float* dst = (which == 0) ? qws : (which == 1) ? kws : vws;
                *(float4*)&dst[(((size_t)bb * NHEAD + h) * SEQ_T + t) * DHEAD + d0] = o;
            }
        }
    }
}

// ---------------------------------------------------------------------------
// Kernel 2: causal flash attention, fp32. One block per (b, h, 64-row q-tile).
// 256 threads = 16x16 grid; each thread owns 4 rows x 4 cols.
// ---------------------------------------------------------------------------
__global__ __launch_bounds__(256) void k_attn(
    const float* __restrict__ qg, const float* __restrict__ kg,
    const float* __restrict__ vg, float* __restrict__ og)
{
    __shared__ float Qs[64][68];
    __shared__ float KsT[64][68];   // transposed: KsT[d][n]
    __shared__ float Vs[64][68];
    __shared__ float Ps[64][68];

    const int tid = threadIdx.x;
    const int tx = tid & 15, ty = tid >> 4;
    const int qt = blockIdx.x, h = blockIdx.y, b = blockIdx.z;
    const size_t base = ((size_t)b * NHEAD + h) * SEQ_T * DHEAD;

    // Load Q tile (rows qt*64..+63)
    #pragma unroll
    for (int i = 0; i < 4; i++) {
        const int r = (tid >> 4) + i * 16;
        const int d4 = (tid & 15) * 4;
        *(float4*)&Qs[r][d4] =
            *(const float4*)&qg[base + (size_t)(qt * 64 + r) * DHEAD + d4];
    }

    float m_i[4], l_i[4], O[4][4];
    #pragma unroll
    for (int i = 0; i < 4; i++) {
        m_i[i] = -INFINITY; l_i[i] = 0.f;
        #pragma unroll
        for (int j = 0; j < 4; j++) O[i][j] = 0.f;
    }

    for (int jt = 0; jt <= qt; jt++) {
        __syncthreads();   // prev PV done with Vs/Ps
        // Load K (transposed) and V tiles
        #pragma unroll
        for (int i = 0; i < 4; i++) {
            const int r = (tid >> 4) + i * 16;
            const int d4 = (tid & 15) * 4;
            float4 kv = *(const float4*)&kg[base + (size_t)(jt * 64 + r) * DHEAD + d4];
            KsT[d4 + 0][r] = kv.x; KsT[d4 + 1][r] = kv.y;
            KsT[d4 + 2][r] = kv.z; KsT[d4 + 3][r] = kv.w;
            *(float4*)&Vs[r][d4] =
                *(const float4*)&vg[base + (size_t)(jt * 64 + r) * DHEAD + d4];
        }
        __syncthreads();

        // S = Q K^T (scale already folded into q)
        float s[4][4];
        #pragma unroll
        for (int i = 0; i < 4; i++)
            #pragma unroll
            for (int j = 0; j < 4; j++) s[i][j] = 0.f;
        #pragma unroll
        for (int k4 = 0; k4 < 64; k4 += 4) {
            float4 qv[4], kv[4];
            #pragma unroll
            for (int i = 0; i < 4; i++) qv[i] = *(const float4*)&Qs[ty * 4 + i][k4];
            #pragma unroll
            for (int kk = 0; kk < 4; kk++) kv[kk] = *(const float4*)&KsT[k4 + kk][tx * 4];
            #pragma unroll
            for (int kk = 0; kk < 4; kk++) {
                #pragma unroll
                for (int i = 0; i < 4; i++) {
                    const float qq = ((const float*)&qv[i])[kk];
                    s[i][0] = fmaf(qq, kv[kk].x, s[i][0]);
                    s[i][1] = fmaf(qq, kv[kk].y, s[i][1]);
                    s[i][2] = fmaf(qq, kv[kk].z, s[i][2]);
                    s[i][3] = fmaf(qq, kv[kk].w, s[i][3]);
                }
            }
        }

        // causal mask on diagonal tile
        if (jt == qt) {
            #pragma unroll
            for (int i = 0; i < 4; i++)
                #pragma unroll
                for (int j = 0; j < 4; j++)
                    if (tx * 4 + j > ty * 4 + i) s[i][j] = -INFINITY;
        }

        // online softmax update (row reductions over the 16 tx lanes)
        float mnew[4], p[4][4], rs[4];
        #pragma unroll
        for (int i = 0; i < 4; i++) {
            float rm = fmaxf(fmaxf(s[i][0], s[i][1]), fmaxf(s[i][2], s[i][3]));
            #pragma unroll
            for (int off = 1; off < 16; off <<= 1)
                rm = fmaxf(rm, __shfl_xor(rm, off, 64));
            mnew[i] = fmaxf(m_i[i], rm);
        }
        #pragma unroll
        for (int i = 0; i < 4; i++) {
            rs[i] = 0.f;
            #pragma unroll
            for (int j = 0; j < 4; j++) {
                p[i][j] = __expf(s[i][j] - mnew[i]);
                rs[i] += p[i][j];
            }
            #pragma unroll
            for (int off = 1; off < 16; off <<= 1)
                rs[i] += __shfl_xor(rs[i], off, 64);
            const float alpha = __expf(m_i[i] - mnew[i]);  // 0 on first tile
            l_i[i] = l_i[i] * alpha + rs[i];
            m_i[i] = mnew[i];
            #pragma unroll
            for (int j = 0; j < 4; j++) O[i][j] *= alpha;
            float4 p4 = make_float4(p[i][0], p[i][1], p[i][2], p[i][3]);
            *(float4*)&Ps[ty * 4 + i][tx * 4] = p4;
        }
        __syncthreads();

        // O += P V
        #pragma unroll
        for (int n4 = 0; n4 < 64; n4 += 4) {
            float4 vv[4], pv[4];
            #pragma unroll
            for (int kk = 0; kk < 4; kk++) vv[kk] = *(const float4*)&Vs[n4 + kk][tx * 4];
            #pragma unroll
            for (int i = 0; i < 4; i++) pv[i] = *(const float4*)&Ps[ty * 4 + i][n4];
            #pragma unroll
            for (int kk = 0; kk < 4; kk++) {
                #pragma unroll
                for (int i = 0; i < 4; i++) {
                    const float pp = ((const float*)&pv[i])[kk];
                    O[i][0] = fmaf(pp, vv[kk].x, O[i][0]);
                    O[i][1] = fmaf(pp, vv[kk].y, O[i][1]);
                    O[i][2] = fmaf(pp, vv[kk].z, O[i][2]);
                    O[i][3] = fmaf(pp, vv[kk].w, O[i][3]);
                }
            }
        }
    }

    // normalize + store in x-layout (b, t, h*64+d) for the proj GEMM
    #pragma unroll
    for (int i = 0; i < 4; i++) {
        const int tq = qt * 64 + ty * 4 + i;
        const float inv = 1.0f / l_i[i];
        float4 o = make_float4(O[i][0] * inv, O[i][1] * inv, O[i][2] * inv, O[i][3] * inv);
        *(float4*)&og[((size_t)b * SEQ_T + tq) * DMODEL + h * DHEAD + tx * 4] = o;
    }
}

// ---------------------------------------------------------------------------
// Kernel 3: out = attn_out @ Wproj  (4096x1024 @ 1024x1024)
// ---------------------------------------------------------------------------
__global__ __launch_bounds__(256) void k_proj(
    const float* __restrict__ A, const float* __restrict__ W, float* __restrict__ C)
{
    __shared__ float As[8][128];
    __shared__ float Bs[8][128];
    const int tid = threadIdx.x;
    const int tx = tid & 15, ty = tid >> 4;
    const int M0 = blockIdx.y * 128, N0 = blockIdx.x * 128;

    float acc[8][8];
    #pragma unroll
    for (int i = 0; i < 8; i++)
        #pragma unroll
        for (int j = 0; j < 8; j++) acc[i][j] = 0.f;

    const int arow = tid >> 1, acol = (tid & 1) * 4;
    const int brow = tid >> 5, bcol = (tid & 31) * 4;
    const float* Aptr = A + (size_t)(M0 + arow) * 1024 + acol;
    const float* Bptr = W + (size_t)brow * 1024 + N0 + bcol;

    for (int kt = 0; kt < 1024; kt += 8) {
        float4 a = *(const float4*)(Aptr + kt);
        float4 b = *(const float4*)(Bptr + (size_t)kt * 1024);
        __syncthreads();
        As[acol + 0][arow] = a.x; As[acol + 1][arow] = a.y;
        As[acol + 2][arow] = a.z; As[acol + 3][arow] = a.w;
        *(float4*)&Bs[brow][bcol] = b;
        __syncthreads();
        #pragma unroll
        for (int k = 0; k < 8; k++) {
            float4 a0 = *(const float4*)&As[k][ty * 4];
            float4 a1 = *(const float4*)&As[k][64 + ty * 4];
            float4 b0 = *(const float4*)&Bs[k][tx * 4];
            float4 b1 = *(const float4*)&Bs[k][64 + tx * 4];
            float am[8] = {a0.x, a0.y, a0.z, a0.w, a1.x, a1.y, a1.z, a1.w};
            float bv[8] = {b0.x, b0.y, b0.z, b0.w, b1.x, b1.y, b1.z, b1.w};
            #pragma unroll
            for (int i = 0; i < 8; i++)
                #pragma unroll
                for (int j = 0; j < 8; j++)
                    acc[i][j] = fmaf(am[i], bv[j], acc[i][j]);
        }
    }

    #pragma unroll
    for (int rg = 0; rg < 2; rg++) {
        #pragma unroll
        for (int i = 0; i < 4; i++) {
            const int m = M0 + rg * 64 + ty * 4 + i;
            #pragma unroll
            for (int cg = 0; cg < 2; cg++) {
                const int n = N0 + cg * 64 + tx * 4;
                float4 o = make_float4(acc[rg * 4 + i][cg * 4 + 0],
                                       acc[rg * 4 + i][cg * 4 + 1],
                                       acc[rg * 4 + i][cg * 4 + 2],
                                       acc[rg * 4 + i][cg * 4 + 3]);
                *(float4*)&C[(size_t)m * 1024 + n] = o;
            }
        }
    }
}

// ---------------------------------------------------------------------------
extern "C" void kernel_launch(void* const* d_in, const int* in_sizes, int n_in,
                              void* d_out, int out_size, void* d_ws, size_t ws_size,
                              hipStream_t stream)
{
    const float* x     = (const float*)d_in[0];
    const float* cosb  = (const float*)d_in[1];
    const float* sinb  = (const float*)d_in[2];
    const float* wqkv  = (const float*)d_in[3];
    const float* wproj = (const float*)d_in[4];
    float* out = (float*)d_out;

    float* ws  = (float*)d_ws;
    float* qws = ws;                    // 4M floats (B,H,T,D)
    float* kws = ws + 4194304;
    float* vws = ws + 8388608;
    float* aws = ws + 12582912;         // attn out, x-layout (4096,1024)

    k_qkv_rope<<<dim3(QKV_N / 128, MROWS / 128), 256, 0, stream>>>(
        x, wqkv, cosb, sinb, qws, kws, vws);
    k_attn<<<dim3(SEQ_T / 64, NHEAD, 4), 256, 0, stream>>>(qws, kws, vws, aws);
    k_proj<<<dim3(DMODEL / 128, MROWS / 128), 256, 0, stream>>>(aws, wproj, out);
}

// Round 3
// 540.203 us; speedup vs baseline: 1.6716x; 1.6716x over previous
//
#include <hip/hip_runtime.h>
#include <hip/hip_bf16.h>
#include <math.h>

// Problem constants (B=4, T=1024, D_MODEL=1024, H=16, D_HEAD=64)
#define SEQ_T   1024
#define DMODEL  1024
#define NHEAD   16
#define DHEAD   64
#define MROWS   4096            // B*T
#define QKV_N   3072

typedef __attribute__((ext_vector_type(8))) short  short8;   // 8 bf16 = 4 VGPR
typedef __attribute__((ext_vector_type(4))) float  f32x4;    // MFMA C/D frag
typedef __attribute__((ext_vector_type(4))) unsigned short us4;

__device__ __forceinline__ unsigned short f2bf(float f) {
    unsigned u = __float_as_uint(f);
    u += 0x7FFF + ((u >> 16) & 1);          // RNE
    return (unsigned short)(u >> 16);
}
__device__ __forceinline__ float bf2f(unsigned short u) {
    return __uint_as_float((unsigned)u << 16);
}

__device__ __forceinline__ void gload_lds16(const void* g, void* lds) {
    __builtin_amdgcn_global_load_lds(
        (const __attribute__((address_space(1))) void*)g,
        (__attribute__((address_space(3))) void*)lds, 16, 0, 0);
}

// ---------------------------------------------------------------------------
// fp32 -> bf16 elementwise (8 elems/thread)
// ---------------------------------------------------------------------------
__global__ __launch_bounds__(256) void k_f32_to_bf16(
    const float* __restrict__ in, unsigned short* __restrict__ out, int n8)
{
    const int f = blockIdx.x * 256 + threadIdx.x;
    if (f >= n8) return;
    const float4 a = ((const float4*)in)[f * 2];
    const float4 b = ((const float4*)in)[f * 2 + 1];
    short8 o;
    o[0] = (short)f2bf(a.x); o[1] = (short)f2bf(a.y);
    o[2] = (short)f2bf(a.z); o[3] = (short)f2bf(a.w);
    o[4] = (short)f2bf(b.x); o[5] = (short)f2bf(b.y);
    o[6] = (short)f2bf(b.z); o[7] = (short)f2bf(b.w);
    *(short8*)&out[f * 8] = o;
}

// ---------------------------------------------------------------------------
// W[1024][N] fp32  ->  Wt[N][1024] bf16   (32x32 LDS-tiled transpose)
// ---------------------------------------------------------------------------
__global__ __launch_bounds__(256) void k_transpose_bf16(
    const float* __restrict__ in, unsigned short* __restrict__ out, int N)
{
    __shared__ float t[32][33];
    const int K0 = blockIdx.y * 32, N0 = blockIdx.x * 32;
    const int tid = threadIdx.x;
    const int row = tid >> 3, c4 = (tid & 7) * 4;
    const float4 v = *(const float4*)&in[(size_t)(K0 + row) * N + N0 + c4];
    t[c4 + 0][row] = v.x; t[c4 + 1][row] = v.y;
    t[c4 + 2][row] = v.z; t[c4 + 3][row] = v.w;
    __syncthreads();
    us4 o;
    o[0] = f2bf(t[row][c4 + 0]); o[1] = f2bf(t[row][c4 + 1]);
    o[2] = f2bf(t[row][c4 + 2]); o[3] = f2bf(t[row][c4 + 3]);
    *(us4*)&out[(size_t)(N0 + row) * 1024 + K0 + c4] = o;
}

// ---------------------------------------------------------------------------
// Shared MFMA mainloop: C(128x128) += A(128xK) * B^T(128xK), K=1024, BK=32.
// A: [M][1024] bf16 row-major;  Bt: [N][1024] bf16 row-major (pre-transposed).
// 256 thr = 4 waves (2x2), each wave 64x64 via 4x4 frags of 16x16x32 MFMA.
// Single-buffer, 2 barriers/K-step (m97 structure), global_load_lds width 16.
// ---------------------------------------------------------------------------
__device__ __forceinline__ void gemm_mainloop(
    const unsigned short* __restrict__ A, const unsigned short* __restrict__ Bt,
    int M0, int N0, unsigned short* As, unsigned short* Bs, f32x4 acc[4][4])
{
    const int tid  = threadIdx.x;
    const int lane = tid & 63, wave = tid >> 6;
    const int wr = wave >> 1, wc = wave & 1;
    const int l15 = lane & 15, l4 = lane >> 4;

    for (int kt = 0; kt < 1024; kt += 32) {
        __syncthreads();                       // waves done reading LDS
        #pragma unroll
        for (int is = 0; is < 2; is++) {
            const int f = is * 256 + tid;      // 0..511
            const int row = f >> 2, seg = f & 3;
            gload_lds16(A  + (size_t)(M0 + row) * 1024 + kt + seg * 8,
                        (char*)As + is * 4096 + wave * 1024);
            gload_lds16(Bt + (size_t)(N0 + row) * 1024 + kt + seg * 8,
                        (char*)Bs + is * 4096 + wave * 1024);
        }
        __syncthreads();                       // drains vmcnt(0)

        short8 af[4], bfr[4];
        #pragma unroll
        for (int m = 0; m < 4; m++)
            af[m] = *(const short8*)((const char*)As +
                     ((wr * 64 + m * 16 + l15) * 64 + l4 * 16));
        #pragma unroll
        for (int n = 0; n < 4; n++)
            bfr[n] = *(const short8*)((const char*)Bs +
                     ((wc * 64 + n * 16 + l15) * 64 + l4 * 16));
        #pragma unroll
        for (int m = 0; m < 4; m++)
            #pragma unroll
            for (int n = 0; n < 4; n++)
                acc[m][n] = __builtin_amdgcn_mfma_f32_16x16x32_bf16(
                    af[m], bfr[n], acc[m][n], 0, 0, 0);
    }
}

// ---------------------------------------------------------------------------
// qkv GEMM + fused RoPE epilogue -> q,k,v bf16 in (B,H,T,D) layout.
// C-frag layout (m89): col = lane&15, row = (lane>>4)*4 + reg.
// RoPE partner column (col^1) lives in lane^1 -> shfl_xor(.,1).
// ---------------------------------------------------------------------------
__global__ __launch_bounds__(256) void k_gemm_qkv(
    const unsigned short* __restrict__ Xbf, const unsigned short* __restrict__ Wt,
    const float* __restrict__ COS, const float* __restrict__ SIN,
    unsigned short* __restrict__ qws, unsigned short* __restrict__ kws,
    unsigned short* __restrict__ vws)
{
    __shared__ __align__(16) unsigned short As[4096];
    __shared__ __align__(16) unsigned short Bs[4096];
    const int M0 = blockIdx.y * 128, N0 = blockIdx.x * 128;

    f32x4 acc[4][4];
    #pragma unroll
    for (int m = 0; m < 4; m++)
        #pragma unroll
        for (int n = 0; n < 4; n++) acc[m][n] = (f32x4)0.f;

    gemm_mainloop(Xbf, Wt, M0, N0, As, Bs, acc);

    const int tid  = threadIdx.x;
    const int lane = tid & 63, wave = tid >> 6;
    const int wr = wave >> 1, wc = wave & 1;
    const int l15 = lane & 15, l4 = lane >> 4;
    const int which = N0 >> 10;                 // uniform per block: 0=q 1=k 2=v
    unsigned short* dst = (which == 0) ? qws : (which == 1) ? kws : vws;

    #pragma unroll
    for (int m = 0; m < 4; m++) {
        #pragma unroll
        for (int n = 0; n < 4; n++) {
            const int colbase = N0 + wc * 64 + n * 16;
            const int cin = colbase & 1023;
            const int h = cin >> 6;
            const int d = (cin & 63) + l15;
            const int rowbase = M0 + wr * 64 + m * 16 + l4 * 4;
            #pragma unroll
            for (int r = 0; r < 4; r++) {
                const int row = rowbase + r;
                const int bb = row >> 10, t = row & 1023;
                const float v = acc[m][n][r];
                const float p = __shfl_xor(v, 1, 64);
                float o;
                if (which < 2) {
                    const float c = COS[t * 64 + d];
                    const float s = SIN[t * 64 + d];
                    o = (lane & 1) ? fmaf(v, c, p * s) : fmaf(v, c, -(p * s));
                    if (which == 0) o *= 0.125f;     // 1/sqrt(64)
                } else {
                    o = v;
                }
                dst[(((size_t)bb * NHEAD + h) * SEQ_T + t) * DHEAD + d] = f2bf(o);
            }
        }
    }
}

// ---------------------------------------------------------------------------
// proj GEMM -> fp32 out (4096x1024)
// ---------------------------------------------------------------------------
__global__ __launch_bounds__(256) void k_gemm_proj(
    const unsigned short* __restrict__ Abf, const unsigned short* __restrict__ Wt,
    float* __restrict__ C)
{
    __shared__ __align__(16) unsigned short As[4096];
    __shared__ __align__(16) unsigned short Bs[4096];
    const int M0 = blockIdx.y * 128, N0 = blockIdx.x * 128;

    f32x4 acc[4][4];
    #pragma unroll
    for (int m = 0; m < 4; m++)
        #pragma unroll
        for (int n = 0; n < 4; n++) acc[m][n] = (f32x4)0.f;

    gemm_mainloop(Abf, Wt, M0, N0, As, Bs, acc);

    const int tid  = threadIdx.x;
    const int lane = tid & 63, wave = tid >> 6;
    const int wr = wave >> 1, wc = wave & 1;
    const int l15 = lane & 15, l4 = lane >> 4;

    #pragma unroll
    for (int m = 0; m < 4; m++) {
        #pragma unroll
        for (int n = 0; n < 4; n++) {
            const int col = N0 + wc * 64 + n * 16 + l15;
            const int rowbase = M0 + wr * 64 + m * 16 + l4 * 4;
            #pragma unroll
            for (int r = 0; r < 4; r++)
                C[(size_t)(rowbase + r) * 1024 + col] = acc[m][n][r];
        }
    }
}

// ---------------------------------------------------------------------------
// Flash attention (fp32 math, bf16 I/O). One block per (b, h, 64-row q-tile).
// Structurally identical to the passing R1 kernel; only loads/stores changed.
// ---------------------------------------------------------------------------
__global__ __launch_bounds__(256) void k_attn(
    const unsigned short* __restrict__ qg, const unsigned short* __restrict__ kg,
    const unsigned short* __restrict__ vg, unsigned short* __restrict__ og)
{
    __shared__ float Qs[64][68];
    __shared__ float KsT[64][68];   // transposed: KsT[d][n]
    __shared__ float Vs[64][68];
    __shared__ float Ps[64][68];

    const int tid = threadIdx.x;
    const int tx = tid & 15, ty = tid >> 4;
    const int qt = blockIdx.x, h = blockIdx.y, b = blockIdx.z;
    const size_t base = ((size_t)b * NHEAD + h) * SEQ_T * DHEAD;

    // Load Q tile (bf16x8 -> f32)
    #pragma unroll
    for (int i = 0; i < 2; i++) {
        const int f = i * 256 + tid;
        const int r = f >> 3, d8 = (f & 7) * 8;
        short8 v8 = *(const short8*)&qg[base + (size_t)(qt * 64 + r) * DHEAD + d8];
        #pragma unroll
        for (int j = 0; j < 8; j++) Qs[r][d8 + j] = bf2f((unsigned short)v8[j]);
    }

    float m_i[4], l_i[4], O[4][4];
    #pragma unroll
    for (int i = 0; i < 4; i++) {
        m_i[i] = -INFINITY; l_i[i] = 0.f;
        #pragma unroll
        for (int j = 0; j < 4; j++) O[i][j] = 0.f;
    }

    for (int jt = 0; jt <= qt; jt++) {
        __syncthreads();
        #pragma unroll
        for (int i = 0; i < 2; i++) {
            const int f = i * 256 + tid;
            const int r = f >> 3, d8 = (f & 7) * 8;
            short8 kv = *(const short8*)&kg[base + (size_t)(jt * 64 + r) * DHEAD + d8];
            short8 vv = *(const short8*)&vg[base + (size_t)(jt * 64 + r) * DHEAD + d8];
            #pragma unroll
            for (int j = 0; j < 8; j++) {
                KsT[d8 + j][r] = bf2f((unsigned short)kv[j]);
                Vs[r][d8 + j]  = bf2f((unsigned short)vv[j]);
            }
        }
        __syncthreads();

        // S = Q K^T (scale folded into q)
        float s[4][4];
        #pragma unroll
        for (int i = 0; i < 4; i++)
            #pragma unroll
            for (int j = 0; j < 4; j++) s[i][j] = 0.f;
        #pragma unroll
        for (int k4 = 0; k4 < 64; k4 += 4) {
            float4 qv[4], kv[4];
            #pragma unroll
            for (int i = 0; i < 4; i++) qv[i] = *(const float4*)&Qs[ty * 4 + i][k4];
            #pragma unroll
            for (int kk = 0; kk < 4; kk++) kv[kk] = *(const float4*)&KsT[k4 + kk][tx * 4];
            #pragma unroll
            for (int kk = 0; kk < 4; kk++) {
                #pragma unroll
                for (int i = 0; i < 4; i++) {
                    const float qq = ((const float*)&qv[i])[kk];
                    s[i][0] = fmaf(qq, kv[kk].x, s[i][0]);
                    s[i][1] = fmaf(qq, kv[kk].y, s[i][1]);
                    s[i][2] = fmaf(qq, kv[kk].z, s[i][2]);
                    s[i][3] = fmaf(qq, kv[kk].w, s[i][3]);
                }
            }
        }

        if (jt == qt) {
            #pragma unroll
            for (int i = 0; i < 4; i++)
                #pragma unroll
                for (int j = 0; j < 4; j++)
                    if (tx * 4 + j > ty * 4 + i) s[i][j] = -INFINITY;
        }

        float mnew[4], p[4][4], rs[4];
        #pragma unroll
        for (int i = 0; i < 4; i++) {
            float rm = fmaxf(fmaxf(s[i][0], s[i][1]), fmaxf(s[i][2], s[i][3]));
            #pragma unroll
            for (int off = 1; off < 16; off <<= 1)
                rm = fmaxf(rm, __shfl_xor(rm, off, 64));
            mnew[i] = fmaxf(m_i[i], rm);
        }
        #pragma unroll
        for (int i = 0; i < 4; i++) {
            rs[i] = 0.f;
            #pragma unroll
            for (int j = 0; j < 4; j++) {
                p[i][j] = __expf(s[i][j] - mnew[i]);
                rs[i] += p[i][j];
            }
            #pragma unroll
            for (int off = 1; off < 16; off <<= 1)
                rs[i] += __shfl_xor(rs[i], off, 64);
            const float alpha = __expf(m_i[i] - mnew[i]);
            l_i[i] = l_i[i] * alpha + rs[i];
            m_i[i] = mnew[i];
            #pragma unroll
            for (int j = 0; j < 4; j++) O[i][j] *= alpha;
            float4 p4 = make_float4(p[i][0], p[i][1], p[i][2], p[i][3]);
            *(float4*)&Ps[ty * 4 + i][tx * 4] = p4;
        }
        __syncthreads();

        // O += P V
        #pragma unroll
        for (int n4 = 0; n4 < 64; n4 += 4) {
            float4 vv[4], pv[4];
            #pragma unroll
            for (int kk = 0; kk < 4; kk++) vv[kk] = *(const float4*)&Vs[n4 + kk][tx * 4];
            #pragma unroll
            for (int i = 0; i < 4; i++) pv[i] = *(const float4*)&Ps[ty * 4 + i][n4];
            #pragma unroll
            for (int kk = 0; kk < 4; kk++) {
                #pragma unroll
                for (int i = 0; i < 4; i++) {
                    const float pp = ((const float*)&pv[i])[kk];
                    O[i][0] = fmaf(pp, vv[kk].x, O[i][0]);
                    O[i][1] = fmaf(pp, vv[kk].y, O[i][1]);
                    O[i][2] = fmaf(pp, vv[kk].z, O[i][2]);
                    O[i][3] = fmaf(pp, vv[kk].w, O[i][3]);
                }
            }
        }
    }

    // normalize + store bf16 in x-layout (b, t, h*64+d) for proj
    #pragma unroll
    for (int i = 0; i < 4; i++) {
        const int tq = qt * 64 + ty * 4 + i;
        const float inv = 1.0f / l_i[i];
        us4 o4;
        o4[0] = f2bf(O[i][0] * inv); o4[1] = f2bf(O[i][1] * inv);
        o4[2] = f2bf(O[i][2] * inv); o4[3] = f2bf(O[i][3] * inv);
        *(us4*)&og[((size_t)b * SEQ_T + tq) * DMODEL + h * DHEAD + tx * 4] = o4;
    }
}

// ---------------------------------------------------------------------------
extern "C" void kernel_launch(void* const* d_in, const int* in_sizes, int n_in,
                              void* d_out, int out_size, void* d_ws, size_t ws_size,
                              hipStream_t stream)
{
    const float* x     = (const float*)d_in[0];
    const float* cosb  = (const float*)d_in[1];
    const float* sinb  = (const float*)d_in[2];
    const float* wqkv  = (const float*)d_in[3];
    const float* wproj = (const float*)d_in[4];
    float* out = (float*)d_out;

    char* ws = (char*)d_ws;                     // 48 MB used
    unsigned short* qbf    = (unsigned short*)(ws);            //  8 MB (B,H,T,D)
    unsigned short* kbf    = (unsigned short*)(ws + (8u<<20));  //  8 MB
    unsigned short* vbf    = (unsigned short*)(ws + (16u<<20)); //  8 MB
    unsigned short* xbf    = (unsigned short*)(ws + (24u<<20)); //  8 MB (4096,1024)
    unsigned short* wqkvt  = (unsigned short*)(ws + (32u<<20)); //  6 MB (3072,1024)
    unsigned short* wprojt = (unsigned short*)(ws + (38u<<20)); //  2 MB (1024,1024)
    unsigned short* awsbf  = (unsigned short*)(ws + (40u<<20)); //  8 MB (4096,1024)

    k_f32_to_bf16<<<2048, 256, 0, stream>>>(x, xbf, 524288);
    k_transpose_bf16<<<dim3(QKV_N / 32, 1024 / 32), 256, 0, stream>>>(wqkv, wqkvt, QKV_N);
    k_transpose_bf16<<<dim3(1024 / 32, 1024 / 32), 256, 0, stream>>>(wproj, wprojt, 1024);

    k_gemm_qkv<<<dim3(QKV_N / 128, MROWS / 128), 256, 0, stream>>>(
        xbf, wqkvt, cosb, sinb, qbf, kbf, vbf);
    k_attn<<<dim3(SEQ_T / 64, NHEAD, 4), 256, 0, stream>>>(qbf, kbf, vbf, awsbf);
    k_gemm_proj<<<dim3(DMODEL / 128, MROWS / 128), 256, 0, stream>>>(awsbf, wprojt, out);
}

// Round 4
// 225.326 us; speedup vs baseline: 4.0076x; 2.3974x over previous
//
#include <hip/hip_runtime.h>
#include <hip/hip_bf16.h>
#include <math.h>

// Problem constants (B=4, T=1024, D_MODEL=1024, H=16, D_HEAD=64)
#define SEQ_T   1024
#define DMODEL  1024
#define NHEAD   16
#define DHEAD   64
#define MROWS   4096            // B*T
#define QKV_N   3072

typedef __attribute__((ext_vector_type(8))) short  short8;   // 8 bf16 = 4 VGPR
typedef __attribute__((ext_vector_type(4))) float  f32x4;    // MFMA C/D frag
typedef __attribute__((ext_vector_type(4))) unsigned short us4;

__device__ __forceinline__ unsigned short f2bf(float f) {
    unsigned u = __float_as_uint(f);
    u += 0x7FFF + ((u >> 16) & 1);          // RNE
    return (unsigned short)(u >> 16);
}
__device__ __forceinline__ float bf2f(unsigned short u) {
    return __uint_as_float((unsigned)u << 16);
}

__device__ __forceinline__ void gload_lds16(const void* g, void* lds) {
    __builtin_amdgcn_global_load_lds(
        (const __attribute__((address_space(1))) void*)g,
        (__attribute__((address_space(3))) void*)lds, 16, 0, 0);
}

// ---------------------------------------------------------------------------
// fp32 -> bf16 elementwise (8 elems/thread)
// ---------------------------------------------------------------------------
__global__ __launch_bounds__(256) void k_f32_to_bf16(
    const float* __restrict__ in, unsigned short* __restrict__ out, int n8)
{
    const int f = blockIdx.x * 256 + threadIdx.x;
    if (f >= n8) return;
    const float4 a = ((const float4*)in)[f * 2];
    const float4 b = ((const float4*)in)[f * 2 + 1];
    short8 o;
    o[0] = (short)f2bf(a.x); o[1] = (short)f2bf(a.y);
    o[2] = (short)f2bf(a.z); o[3] = (short)f2bf(a.w);
    o[4] = (short)f2bf(b.x); o[5] = (short)f2bf(b.y);
    o[6] = (short)f2bf(b.z); o[7] = (short)f2bf(b.w);
    *(short8*)&out[f * 8] = o;
}

// ---------------------------------------------------------------------------
// W[1024][N] fp32  ->  Wt[N][1024] bf16   (32x32 LDS-tiled transpose)
// ---------------------------------------------------------------------------
__global__ __launch_bounds__(256) void k_transpose_bf16(
    const float* __restrict__ in, unsigned short* __restrict__ out, int N)
{
    __shared__ float t[32][33];
    const int K0 = blockIdx.y * 32, N0 = blockIdx.x * 32;
    const int tid = threadIdx.x;
    const int row = tid >> 3, c4 = (tid & 7) * 4;
    const float4 v = *(const float4*)&in[(size_t)(K0 + row) * N + N0 + c4];
    t[c4 + 0][row] = v.x; t[c4 + 1][row] = v.y;
    t[c4 + 2][row] = v.z; t[c4 + 3][row] = v.w;
    __syncthreads();
    us4 o;
    o[0] = f2bf(t[row][c4 + 0]); o[1] = f2bf(t[row][c4 + 1]);
    o[2] = f2bf(t[row][c4 + 2]); o[3] = f2bf(t[row][c4 + 3]);
    *(us4*)&out[(size_t)(N0 + row) * 1024 + K0 + c4] = o;
}

// ---------------------------------------------------------------------------
// Shared MFMA mainloop: C(128x128) += A(128xK) * B^T(128xK), K=1024, BK=32.
// ---------------------------------------------------------------------------
__device__ __forceinline__ void gemm_mainloop(
    const unsigned short* __restrict__ A, const unsigned short* __restrict__ Bt,
    int M0, int N0, unsigned short* As, unsigned short* Bs, f32x4 acc[4][4])
{
    const int tid  = threadIdx.x;
    const int lane = tid & 63, wave = tid >> 6;
    const int wr = wave >> 1, wc = wave & 1;
    const int l15 = lane & 15, l4 = lane >> 4;

    for (int kt = 0; kt < 1024; kt += 32) {
        __syncthreads();                       // waves done reading LDS
        #pragma unroll
        for (int is = 0; is < 2; is++) {
            const int f = is * 256 + tid;      // 0..511
            const int row = f >> 2, seg = f & 3;
            gload_lds16(A  + (size_t)(M0 + row) * 1024 + kt + seg * 8,
                        (char*)As + is * 4096 + wave * 1024);
            gload_lds16(Bt + (size_t)(N0 + row) * 1024 + kt + seg * 8,
                        (char*)Bs + is * 4096 + wave * 1024);
        }
        __syncthreads();                       // drains vmcnt(0)

        short8 af[4], bfr[4];
        #pragma unroll
        for (int m = 0; m < 4; m++)
            af[m] = *(const short8*)((const char*)As +
                     ((wr * 64 + m * 16 + l15) * 64 + l4 * 16));
        #pragma unroll
        for (int n = 0; n < 4; n++)
            bfr[n] = *(const short8*)((const char*)Bs +
                     ((wc * 64 + n * 16 + l15) * 64 + l4 * 16));
        #pragma unroll
        for (int m = 0; m < 4; m++)
            #pragma unroll
            for (int n = 0; n < 4; n++)
                acc[m][n] = __builtin_amdgcn_mfma_f32_16x16x32_bf16(
                    af[m], bfr[n], acc[m][n], 0, 0, 0);
    }
}

// ---------------------------------------------------------------------------
// qkv GEMM + fused RoPE epilogue.
// q,k -> (B,H,T,D) bf16 (roped; q scaled 1/8).  v -> TRANSPOSED (B,H,D,T) bf16.
// C-frag layout (m89): col = lane&15, row = (lane>>4)*4 + reg.
// ---------------------------------------------------------------------------
__global__ __launch_bounds__(256) void k_gemm_qkv(
    const unsigned short* __restrict__ Xbf, const unsigned short* __restrict__ Wt,
    const float* __restrict__ COS, const float* __restrict__ SIN,
    unsigned short* __restrict__ qws, unsigned short* __restrict__ kws,
    unsigned short* __restrict__ vws)
{
    __shared__ __align__(16) unsigned short As[4096];
    __shared__ __align__(16) unsigned short Bs[4096];
    const int M0 = blockIdx.y * 128, N0 = blockIdx.x * 128;

    f32x4 acc[4][4];
    #pragma unroll
    for (int m = 0; m < 4; m++)
        #pragma unroll
        for (int n = 0; n < 4; n++) acc[m][n] = (f32x4)0.f;

    gemm_mainloop(Xbf, Wt, M0, N0, As, Bs, acc);

    const int tid  = threadIdx.x;
    const int lane = tid & 63, wave = tid >> 6;
    const int wr = wave >> 1, wc = wave & 1;
    const int l15 = lane & 15, l4 = lane >> 4;
    const int which = N0 >> 10;                 // uniform per block: 0=q 1=k 2=v

    if (which == 2) {
        // V: store transposed (B,H,D,T); 4 C-regs = 4 consecutive t -> us4.
        #pragma unroll
        for (int m = 0; m < 4; m++) {
            const int rowbase = M0 + wr * 64 + m * 16 + l4 * 4;
            const int bb = rowbase >> 10, t0 = rowbase & 1023;
            #pragma unroll
            for (int n = 0; n < 4; n++) {
                const int cin = (N0 + wc * 64 + n * 16) & 1023;
                const int hh = cin >> 6, d = (cin & 63) + l15;
                us4 o4;
                #pragma unroll
                for (int r = 0; r < 4; r++) o4[r] = f2bf(acc[m][n][r]);
                *(us4*)&vws[(((size_t)bb * NHEAD + hh) * DHEAD + d) * SEQ_T + t0] = o4;
            }
        }
    } else {
        unsigned short* dst = (which == 0) ? qws : kws;
        #pragma unroll
        for (int m = 0; m < 4; m++) {
            #pragma unroll
            for (int n = 0; n < 4; n++) {
                const int cin = (N0 + wc * 64 + n * 16) & 1023;
                const int hh = cin >> 6;
                const int d = (cin & 63) + l15;
                const int rowbase = M0 + wr * 64 + m * 16 + l4 * 4;
                #pragma unroll
                for (int r = 0; r < 4; r++) {
                    const int row = rowbase + r;
                    const int bb = row >> 10, t = row & 1023;
                    const float v = acc[m][n][r];
                    const float p = __shfl_xor(v, 1, 64);
                    const float c = COS[t * 64 + d];
                    const float s = SIN[t * 64 + d];
                    float o = (lane & 1) ? fmaf(v, c, p * s) : fmaf(v, c, -(p * s));
                    if (which == 0) o *= 0.125f;     // 1/sqrt(64)
                    dst[(((size_t)bb * NHEAD + hh) * SEQ_T + t) * DHEAD + d] = f2bf(o);
                }
            }
        }
    }
}

// ---------------------------------------------------------------------------
// proj GEMM -> fp32 out (4096x1024)
// ---------------------------------------------------------------------------
__global__ __launch_bounds__(256) void k_gemm_proj(
    const unsigned short* __restrict__ Abf, const unsigned short* __restrict__ Wt,
    float* __restrict__ C)
{
    __shared__ __align__(16) unsigned short As[4096];
    __shared__ __align__(16) unsigned short Bs[4096];
    const int M0 = blockIdx.y * 128, N0 = blockIdx.x * 128;

    f32x4 acc[4][4];
    #pragma unroll
    for (int m = 0; m < 4; m++)
        #pragma unroll
        for (int n = 0; n < 4; n++) acc[m][n] = (f32x4)0.f;

    gemm_mainloop(Abf, Wt, M0, N0, As, Bs, acc);

    const int tid  = threadIdx.x;
    const int lane = tid & 63, wave = tid >> 6;
    const int wr = wave >> 1, wc = wave & 1;
    const int l15 = lane & 15, l4 = lane >> 4;

    #pragma unroll
    for (int m = 0; m < 4; m++) {
        #pragma unroll
        for (int n = 0; n < 4; n++) {
            const int col = N0 + wc * 64 + n * 16 + l15;
            const int rowbase = M0 + wr * 64 + m * 16 + l4 * 4;
            #pragma unroll
            for (int r = 0; r < 4; r++)
                C[(size_t)(rowbase + r) * 1024 + col] = acc[m][n][r];
        }
    }
}

// ---------------------------------------------------------------------------
// MFMA flash attention. Block = (qt 64 rows, h, b); 4 waves, 16 q-rows each.
// Q in regs; K (T,D) and Vt (D,T) tiles in XOR-swizzled LDS (pre-swizzled
// global source, linear global_load_lds dest, swizzled ds_read — rule #21).
// S/P in C-layout regs; softmax via 4x shfl_xor; P via per-wave LDS strip.
// ---------------------------------------------------------------------------
__global__ __launch_bounds__(256) void k_attn(
    const unsigned short* __restrict__ qg, const unsigned short* __restrict__ kg,
    const unsigned short* __restrict__ vtg, unsigned short* __restrict__ og)
{
    __shared__ __align__(16) unsigned short Ks[4096];    // 64 k-rows x 64 d  (swz)
    __shared__ __align__(16) unsigned short Vts[4096];   // 64 d-rows x 64 t  (swz)
    __shared__ __align__(16) unsigned short Ps[4][1024]; // per-wave 16q x 64k (swz)

    const int tid  = threadIdx.x;
    const int lane = tid & 63, w = tid >> 6;
    const int l15 = lane & 15, l4 = lane >> 4, l7 = lane & 7;
    const int qt = blockIdx.x, h = blockIdx.y, b = blockIdx.z;
    const size_t hb     = (size_t)b * NHEAD + h;
    const size_t qkbase = hb * SEQ_T * DHEAD;   // q,k: (T,D)
    const size_t vtbase = hb * DHEAD * SEQ_T;   // vt:  (D,T)

    // Q A-fragments: row = l15 (within wave's 16-row strip), d = kk*32 + l4*8
    const int qrow = qt * 64 + w * 16 + l15;
    const short8 aq0 = *(const short8*)&qg[qkbase + (size_t)qrow * 64 +      l4 * 8];
    const short8 aq1 = *(const short8*)&qg[qkbase + (size_t)qrow * 64 + 32 + l4 * 8];

    f32x4 O[4];
    float m_i[4], l_i[4];
    #pragma unroll
    for (int nd = 0; nd < 4; nd++) O[nd] = (f32x4)0.f;
    #pragma unroll
    for (int r = 0; r < 4; r++) { m_i[r] = -INFINITY; l_i[r] = 0.f; }

    unsigned short* pw = &Ps[w][0];

    for (int jt = 0; jt <= qt; ++jt) {
        __syncthreads();                       // all waves done reading prev tile
        #pragma unroll
        for (int i = 0; i < 2; i++) {
            const int c = i * 256 + tid;       // 0..511 16B-chunks
            const int row = c >> 3, ps = c & 7;
            const int ls = ps ^ (row & 7);     // inverse-swizzled source seg
            gload_lds16(kg + qkbase + (size_t)(jt * 64 + row) * 64 + ls * 8,
                        (char*)Ks + i * 4096 + w * 1024);
            gload_lds16(vtg + vtbase + (size_t)row * 1024 + jt * 64 + ls * 8,
                        (char*)Vts + i * 4096 + w * 1024);
        }
        __syncthreads();                       // drains vmcnt(0)

        // ---- S = Q K^T ----
        f32x4 S[4];
        #pragma unroll
        for (int n = 0; n < 4; n++) S[n] = (f32x4)0.f;
        #pragma unroll
        for (int n = 0; n < 4; n++) {
            const int krow = n * 16 + l15;     // krow&7 == l7
            const short8 bk0 = *(const short8*)((const char*)Ks +
                                krow * 128 + (((0 + l4) ^ l7) << 4));
            const short8 bk1 = *(const short8*)((const char*)Ks +
                                krow * 128 + (((4 + l4) ^ l7) << 4));
            S[n] = __builtin_amdgcn_mfma_f32_16x16x32_bf16(aq0, bk0, S[n], 0, 0, 0);
            S[n] = __builtin_amdgcn_mfma_f32_16x16x32_bf16(aq1, bk1, S[n], 0, 0, 0);
        }

        // ---- causal mask (diagonal tile only) ----
        if (jt == qt) {
            #pragma unroll
            for (int n = 0; n < 4; n++)
                #pragma unroll
                for (int r = 0; r < 4; r++)
                    if (n * 16 + l15 > w * 16 + l4 * 4 + r) S[n][r] = -INFINITY;
        }

        // ---- online softmax (row r of C-layout; 16-lane group reduce) ----
        #pragma unroll
        for (int r = 0; r < 4; r++) {
            float mx = fmaxf(fmaxf(S[0][r], S[1][r]), fmaxf(S[2][r], S[3][r]));
            #pragma unroll
            for (int off = 1; off < 16; off <<= 1)
                mx = fmaxf(mx, __shfl_xor(mx, off, 64));
            const float mnew  = fmaxf(m_i[r], mx);
            const float alpha = __expf(m_i[r] - mnew);   // 0 on first tile
            m_i[r] = mnew;
            float rs = 0.f;
            #pragma unroll
            for (int n = 0; n < 4; n++) {
                const float p = __expf(S[n][r] - mnew);
                S[n][r] = p;
                rs += p;
            }
            #pragma unroll
            for (int off = 1; off < 16; off <<= 1)
                rs += __shfl_xor(rs, off, 64);
            l_i[r] = l_i[r] * alpha + rs;
            #pragma unroll
            for (int nd = 0; nd < 4; nd++) O[nd][r] *= alpha;
        }

        // ---- P -> bf16 -> per-wave LDS strip (swizzled) ----
        #pragma unroll
        for (int n = 0; n < 4; n++)
            #pragma unroll
            for (int r = 0; r < 4; r++) {
                const int q = l4 * 4 + r;
                const int byteoff = q * 128 + ((n * 32 + l15 * 2) ^ ((q & 7) << 4));
                *(unsigned short*)((char*)pw + byteoff) = f2bf(S[n][r]);
            }

        // ---- O += P V  (A = P strip, B = Vt) ----
        const short8 pa0 = *(const short8*)((const char*)pw +
                            l15 * 128 + (((0 + l4) ^ l7) << 4));
        const short8 pa1 = *(const short8*)((const char*)pw +
                            l15 * 128 + (((4 + l4) ^ l7) << 4));
        #pragma unroll
        for (int nd = 0; nd < 4; nd++) {
            const int drow = nd * 16 + l15;    // drow&7 == l7
            const short8 v0 = *(const short8*)((const char*)Vts +
                               drow * 128 + (((0 + l4) ^ l7) << 4));
            const short8 v1 = *(const short8*)((const char*)Vts +
                               drow * 128 + (((4 + l4) ^ l7) << 4));
            O[nd] = __builtin_amdgcn_mfma_f32_16x16x32_bf16(pa0, v0, O[nd], 0, 0, 0);
            O[nd] = __builtin_amdgcn_mfma_f32_16x16x32_bf16(pa1, v1, O[nd], 0, 0, 0);
        }
    }

    // ---- normalize + store bf16 in x-layout (b, t, h*64+d) for proj ----
    #pragma unroll
    for (int r = 0; r < 4; r++) {
        const float inv = 1.0f / l_i[r];
        const int tq = qt * 64 + w * 16 + l4 * 4 + r;
        #pragma unroll
        for (int nd = 0; nd < 4; nd++) {
            const int d = nd * 16 + l15;
            og[((size_t)b * SEQ_T + tq) * DMODEL + h * 64 + d] = f2bf(O[nd][r] * inv);
        }
    }
}

// ---------------------------------------------------------------------------
extern "C" void kernel_launch(void* const* d_in, const int* in_sizes, int n_in,
                              void* d_out, int out_size, void* d_ws, size_t ws_size,
                              hipStream_t stream)
{
    const float* x     = (const float*)d_in[0];
    const float* cosb  = (const float*)d_in[1];
    const float* sinb  = (const float*)d_in[2];
    const float* wqkv  = (const float*)d_in[3];
    const float* wproj = (const float*)d_in[4];
    float* out = (float*)d_out;

    char* ws = (char*)d_ws;                     // 48 MB used
    unsigned short* qbf    = (unsigned short*)(ws);             //  8 MB (B,H,T,D)
    unsigned short* kbf    = (unsigned short*)(ws + (8u<<20));  //  8 MB (B,H,T,D)
    unsigned short* vtbf   = (unsigned short*)(ws + (16u<<20)); //  8 MB (B,H,D,T)
    unsigned short* xbf    = (unsigned short*)(ws + (24u<<20)); //  8 MB (4096,1024)
    unsigned short* wqkvt  = (unsigned short*)(ws + (32u<<20)); //  6 MB (3072,1024)
    unsigned short* wprojt = (unsigned short*)(ws + (38u<<20)); //  2 MB (1024,1024)
    unsigned short* awsbf  = (unsigned short*)(ws + (40u<<20)); //  8 MB (4096,1024)

    k_f32_to_bf16<<<2048, 256, 0, stream>>>(x, xbf, 524288);
    k_transpose_bf16<<<dim3(QKV_N / 32, 1024 / 32), 256, 0, stream>>>(wqkv, wqkvt, QKV_N);
    k_transpose_bf16<<<dim3(1024 / 32, 1024 / 32), 256, 0, stream>>>(wproj, wprojt, 1024);

    k_gemm_qkv<<<dim3(QKV_N / 128, MROWS / 128), 256, 0, stream>>>(
        xbf, wqkvt, cosb, sinb, qbf, kbf, vtbf);
    k_attn<<<dim3(SEQ_T / 64, NHEAD, 4), 256, 0, stream>>>(qbf, kbf, vtbf, awsbf);
    k_gemm_proj<<<dim3(DMODEL / 128, MROWS / 128), 256, 0, stream>>>(awsbf, wprojt, out);
}

// Round 5
// 198.770 us; speedup vs baseline: 4.5430x; 1.1336x over previous
//
#include <hip/hip_runtime.h>
#include <hip/hip_bf16.h>
#include <math.h>

// Problem constants (B=4, T=1024, D_MODEL=1024, H=16, D_HEAD=64)
#define SEQ_T   1024
#define DMODEL  1024
#define NHEAD   16
#define DHEAD   64
#define MROWS   4096            // B*T
#define QKV_N   3072

typedef __attribute__((ext_vector_type(8))) short  short8;   // 8 bf16 = 4 VGPR
typedef __attribute__((ext_vector_type(4))) float  f32x4;    // MFMA C/D frag
typedef __attribute__((ext_vector_type(4))) unsigned short us4;

__device__ __forceinline__ unsigned short f2bf(float f) {
    unsigned u = __float_as_uint(f);
    u += 0x7FFF + ((u >> 16) & 1);          // RNE
    return (unsigned short)(u >> 16);
}
__device__ __forceinline__ float bf2f(unsigned short u) {
    return __uint_as_float((unsigned)u << 16);
}

__device__ __forceinline__ void gload_lds16(const void* g, void* lds) {
    __builtin_amdgcn_global_load_lds(
        (const __attribute__((address_space(1))) void*)g,
        (__attribute__((address_space(3))) void*)lds, 16, 0, 0);
}

// ---------------------------------------------------------------------------
// fp32 -> bf16 elementwise (8 elems/thread)
// ---------------------------------------------------------------------------
__global__ __launch_bounds__(256) void k_f32_to_bf16(
    const float* __restrict__ in, unsigned short* __restrict__ out, int n8)
{
    const int f = blockIdx.x * 256 + threadIdx.x;
    if (f >= n8) return;
    const float4 a = ((const float4*)in)[f * 2];
    const float4 b = ((const float4*)in)[f * 2 + 1];
    short8 o;
    o[0] = (short)f2bf(a.x); o[1] = (short)f2bf(a.y);
    o[2] = (short)f2bf(a.z); o[3] = (short)f2bf(a.w);
    o[4] = (short)f2bf(b.x); o[5] = (short)f2bf(b.y);
    o[6] = (short)f2bf(b.z); o[7] = (short)f2bf(b.w);
    *(short8*)&out[f * 8] = o;
}

// ---------------------------------------------------------------------------
// W[1024][N] fp32  ->  Wt[N][1024] bf16   (32x32 LDS-tiled transpose)
// ---------------------------------------------------------------------------
__global__ __launch_bounds__(256) void k_transpose_bf16(
    const float* __restrict__ in, unsigned short* __restrict__ out, int N)
{
    __shared__ float t[32][33];
    const int K0 = blockIdx.y * 32, N0 = blockIdx.x * 32;
    const int tid = threadIdx.x;
    const int row = tid >> 3, c4 = (tid & 7) * 4;
    const float4 v = *(const float4*)&in[(size_t)(K0 + row) * N + N0 + c4];
    t[c4 + 0][row] = v.x; t[c4 + 1][row] = v.y;
    t[c4 + 2][row] = v.z; t[c4 + 3][row] = v.w;
    __syncthreads();
    us4 o;
    o[0] = f2bf(t[row][c4 + 0]); o[1] = f2bf(t[row][c4 + 1]);
    o[2] = f2bf(t[row][c4 + 2]); o[3] = f2bf(t[row][c4 + 3]);
    *(us4*)&out[(size_t)(N0 + row) * 1024 + K0 + c4] = o;
}

// ---------------------------------------------------------------------------
// Shared MFMA mainloop: C(128x128) += A(128xK) * B^T(128xK), K=1024, BK=32.
// ---------------------------------------------------------------------------
__device__ __forceinline__ void gemm_mainloop(
    const unsigned short* __restrict__ A, const unsigned short* __restrict__ Bt,
    int M0, int N0, unsigned short* As, unsigned short* Bs, f32x4 acc[4][4])
{
    const int tid  = threadIdx.x;
    const int lane = tid & 63, wave = tid >> 6;
    const int wr = wave >> 1, wc = wave & 1;
    const int l15 = lane & 15, l4 = lane >> 4;

    for (int kt = 0; kt < 1024; kt += 32) {
        __syncthreads();                       // waves done reading LDS
        #pragma unroll
        for (int is = 0; is < 2; is++) {
            const int f = is * 256 + tid;      // 0..511
            const int row = f >> 2, seg = f & 3;
            gload_lds16(A  + (size_t)(M0 + row) * 1024 + kt + seg * 8,
                        (char*)As + is * 4096 + wave * 1024);
            gload_lds16(Bt + (size_t)(N0 + row) * 1024 + kt + seg * 8,
                        (char*)Bs + is * 4096 + wave * 1024);
        }
        __syncthreads();                       // drains vmcnt(0)

        short8 af[4], bfr[4];
        #pragma unroll
        for (int m = 0; m < 4; m++)
            af[m] = *(const short8*)((const char*)As +
                     ((wr * 64 + m * 16 + l15) * 64 + l4 * 16));
        #pragma unroll
        for (int n = 0; n < 4; n++)
            bfr[n] = *(const short8*)((const char*)Bs +
                     ((wc * 64 + n * 16 + l15) * 64 + l4 * 16));
        #pragma unroll
        for (int m = 0; m < 4; m++)
            #pragma unroll
            for (int n = 0; n < 4; n++)
                acc[m][n] = __builtin_amdgcn_mfma_f32_16x16x32_bf16(
                    af[m], bfr[n], acc[m][n], 0, 0, 0);
    }
}

// ---------------------------------------------------------------------------
// qkv GEMM + fused RoPE epilogue.
// q,k -> (B,H,T,D) bf16 (roped; q scaled 1/8).  v -> TRANSPOSED (B,H,D,T) bf16.
// C-frag layout (m89): col = lane&15, row = (lane>>4)*4 + reg.
// ---------------------------------------------------------------------------
__global__ __launch_bounds__(256) void k_gemm_qkv(
    const unsigned short* __restrict__ Xbf, const unsigned short* __restrict__ Wt,
    const float* __restrict__ COS, const float* __restrict__ SIN,
    unsigned short* __restrict__ qws, unsigned short* __restrict__ kws,
    unsigned short* __restrict__ vws)
{
    __shared__ __align__(16) unsigned short As[4096];
    __shared__ __align__(16) unsigned short Bs[4096];
    const int M0 = blockIdx.y * 128, N0 = blockIdx.x * 128;

    f32x4 acc[4][4];
    #pragma unroll
    for (int m = 0; m < 4; m++)
        #pragma unroll
        for (int n = 0; n < 4; n++) acc[m][n] = (f32x4)0.f;

    gemm_mainloop(Xbf, Wt, M0, N0, As, Bs, acc);

    const int tid  = threadIdx.x;
    const int lane = tid & 63, wave = tid >> 6;
    const int wr = wave >> 1, wc = wave & 1;
    const int l15 = lane & 15, l4 = lane >> 4;
    const int which = N0 >> 10;                 // uniform per block: 0=q 1=k 2=v

    if (which == 2) {
        // V: store transposed (B,H,D,T); 4 C-regs = 4 consecutive t -> us4.
        #pragma unroll
        for (int m = 0; m < 4; m++) {
            const int rowbase = M0 + wr * 64 + m * 16 + l4 * 4;
            const int bb = rowbase >> 10, t0 = rowbase & 1023;
            #pragma unroll
            for (int n = 0; n < 4; n++) {
                const int cin = (N0 + wc * 64 + n * 16) & 1023;
                const int hh = cin >> 6, d = (cin & 63) + l15;
                us4 o4;
                #pragma unroll
                for (int r = 0; r < 4; r++) o4[r] = f2bf(acc[m][n][r]);
                *(us4*)&vws[(((size_t)bb * NHEAD + hh) * DHEAD + d) * SEQ_T + t0] = o4;
            }
        }
    } else {
        unsigned short* dst = (which == 0) ? qws : kws;
        #pragma unroll
        for (int m = 0; m < 4; m++) {
            #pragma unroll
            for (int n = 0; n < 4; n++) {
                const int cin = (N0 + wc * 64 + n * 16) & 1023;
                const int hh = cin >> 6;
                const int d = (cin & 63) + l15;
                const int rowbase = M0 + wr * 64 + m * 16 + l4 * 4;
                #pragma unroll
                for (int r = 0; r < 4; r++) {
                    const int row = rowbase + r;
                    const int bb = row >> 10, t = row & 1023;
                    const float v = acc[m][n][r];
                    const float p = __shfl_xor(v, 1, 64);
                    const float c = COS[t * 64 + d];
                    const float s = SIN[t * 64 + d];
                    float o = (lane & 1) ? fmaf(v, c, p * s) : fmaf(v, c, -(p * s));
                    if (which == 0) o *= 0.125f;     // 1/sqrt(64)
                    dst[(((size_t)bb * NHEAD + hh) * SEQ_T + t) * DHEAD + d] = f2bf(o);
                }
            }
        }
    }
}

// ---------------------------------------------------------------------------
// proj GEMM -> fp32 out (4096x1024)
// ---------------------------------------------------------------------------
__global__ __launch_bounds__(256) void k_gemm_proj(
    const unsigned short* __restrict__ Abf, const unsigned short* __restrict__ Wt,
    float* __restrict__ C)
{
    __shared__ __align__(16) unsigned short As[4096];
    __shared__ __align__(16) unsigned short Bs[4096];
    const int M0 = blockIdx.y * 128, N0 = blockIdx.x * 128;

    f32x4 acc[4][4];
    #pragma unroll
    for (int m = 0; m < 4; m++)
        #pragma unroll
        for (int n = 0; n < 4; n++) acc[m][n] = (f32x4)0.f;

    gemm_mainloop(Abf, Wt, M0, N0, As, Bs, acc);

    const int tid  = threadIdx.x;
    const int lane = tid & 63, wave = tid >> 6;
    const int wr = wave >> 1, wc = wave & 1;
    const int l15 = lane & 15, l4 = lane >> 4;

    #pragma unroll
    for (int m = 0; m < 4; m++) {
        #pragma unroll
        for (int n = 0; n < 4; n++) {
            const int col = N0 + wc * 64 + n * 16 + l15;
            const int rowbase = M0 + wr * 64 + m * 16 + l4 * 4;
            #pragma unroll
            for (int r = 0; r < 4; r++)
                C[(size_t)(rowbase + r) * 1024 + col] = acc[m][n][r];
        }
    }
}

// ---------------------------------------------------------------------------
// MFMA flash attention, causal-pair balanced + 2-phase pipelined.
// Block = (pair, h, b) flattened 1D (XCD-swizzled); handles q-tiles
// qtA = pair and qtB = 15-pair  ->  uniform 17 strip-tiles of compute/block.
// 4 waves; wave w owns q-rows [qt*64 + w*16, +16) of each strip.
// K (T,D) and Vt (D,T) tiles double-buffered in XOR-swizzled LDS:
// stage(jt+1) issued BEFORE compute(jt); one __syncthreads (vmcnt drain +
// barrier) per tile  ->  load latency hides under QK/softmax/PV.
// ---------------------------------------------------------------------------
__global__ __launch_bounds__(256) void k_attn(
    const unsigned short* __restrict__ qg, const unsigned short* __restrict__ kg,
    const unsigned short* __restrict__ vtg, unsigned short* __restrict__ og)
{
    __shared__ __align__(16) unsigned short Ks[2][4096];   // [buf][64 krows x 64 d] swz
    __shared__ __align__(16) unsigned short Vts[2][4096];  // [buf][64 drows x 64 t] swz
    __shared__ __align__(16) unsigned short Ps[8][1024];   // [wave*2+strip][16q x 64k] swz

    const int tid  = threadIdx.x;
    const int lane = tid & 63, w = tid >> 6;
    const int l15 = lane & 15, l4 = lane >> 4, l7 = lane & 7;

    // XCD swizzle: 512 blocks, 8 XCDs -> each XCD gets 64 consecutive logical
    // ids = 8 full (b,h) groups -> K/V L2-resident per XCD.
    const int logical = (blockIdx.x & 7) * 64 + (blockIdx.x >> 3);
    const int bh = logical >> 3, pair = logical & 7;
    const int b = bh >> 4, h = bh & 15;
    const int qtA = pair, qtB = 15 - pair;

    const size_t hb     = (size_t)b * NHEAD + h;
    const size_t qkbase = hb * SEQ_T * DHEAD;   // q,k: (T,D)
    const size_t vtbase = hb * DHEAD * SEQ_T;   // vt:  (D,T)

    // Q A-fragments for both strips: row l15, d = frag*32 + l4*8
    const int qrowA = qtA * 64 + w * 16 + l15;
    const int qrowB = qtB * 64 + w * 16 + l15;
    const short8 aqA0 = *(const short8*)&qg[qkbase + (size_t)qrowA * 64 +      l4 * 8];
    const short8 aqA1 = *(const short8*)&qg[qkbase + (size_t)qrowA * 64 + 32 + l4 * 8];
    const short8 aqB0 = *(const short8*)&qg[qkbase + (size_t)qrowB * 64 +      l4 * 8];
    const short8 aqB1 = *(const short8*)&qg[qkbase + (size_t)qrowB * 64 + 32 + l4 * 8];

    f32x4 OA[4], OB[4];
    float mA[4], lA[4], mB[4], lB[4];
    #pragma unroll
    for (int nd = 0; nd < 4; nd++) { OA[nd] = (f32x4)0.f; OB[nd] = (f32x4)0.f; }
    #pragma unroll
    for (int r = 0; r < 4; r++) {
        mA[r] = -INFINITY; lA[r] = 0.f; mB[r] = -INFINITY; lB[r] = 0.f;
    }

    auto STAGE = [&](int jt, int bi) {
        #pragma unroll
        for (int i = 0; i < 2; i++) {
            const int c = i * 256 + tid;       // 16B-chunk id
            const int row = c >> 3, ps = c & 7;
            const int ls = ps ^ (row & 7);     // inverse-swizzled source seg
            gload_lds16(kg + qkbase + (size_t)(jt * 64 + row) * 64 + ls * 8,
                        (char*)&Ks[bi][0] + i * 4096 + w * 1024);
            gload_lds16(vtg + vtbase + (size_t)row * 1024 + jt * 64 + ls * 8,
                        (char*)&Vts[bi][0] + i * 4096 + w * 1024);
        }
    };

    // One causal strip-tile: S = Q K^T, mask, online softmax, P->LDS, O += P V.
    auto STRIP = [&](const short8& aq0, const short8& aq1, f32x4* O,
                     float* m_i, float* l_i, unsigned short* pw,
                     const unsigned short* Kb, const unsigned short* Vb,
                     bool maskdiag) {
        f32x4 S[4];
        #pragma unroll
        for (int n = 0; n < 4; n++) S[n] = (f32x4)0.f;
        #pragma unroll
        for (int n = 0; n < 4; n++) {
            const int krow = n * 16 + l15;     // krow&7 == l7
            const short8 bk0 = *(const short8*)((const char*)Kb +
                                krow * 128 + (((0 + l4) ^ l7) << 4));
            const short8 bk1 = *(const short8*)((const char*)Kb +
                                krow * 128 + (((4 + l4) ^ l7) << 4));
            S[n] = __builtin_amdgcn_mfma_f32_16x16x32_bf16(aq0, bk0, S[n], 0, 0, 0);
            S[n] = __builtin_amdgcn_mfma_f32_16x16x32_bf16(aq1, bk1, S[n], 0, 0, 0);
        }
        if (maskdiag) {
            #pragma unroll
            for (int n = 0; n < 4; n++)
                #pragma unroll
                for (int r = 0; r < 4; r++)
                    if (n * 16 + l15 > w * 16 + l4 * 4 + r) S[n][r] = -INFINITY;
        }
        #pragma unroll
        for (int r = 0; r < 4; r++) {
            float mx = fmaxf(fmaxf(S[0][r], S[1][r]), fmaxf(S[2][r], S[3][r]));
            #pragma unroll
            for (int off = 1; off < 16; off <<= 1)
                mx = fmaxf(mx, __shfl_xor(mx, off, 64));
            const float mnew  = fmaxf(m_i[r], mx);
            const float alpha = __expf(m_i[r] - mnew);   // 0 on first tile
            m_i[r] = mnew;
            float rs = 0.f;
            #pragma unroll
            for (int n = 0; n < 4; n++) {
                const float p = __expf(S[n][r] - mnew);
                S[n][r] = p;
                rs += p;
            }
            #pragma unroll
            for (int off = 1; off < 16; off <<= 1)
                rs += __shfl_xor(rs, off, 64);
            l_i[r] = l_i[r] * alpha + rs;
            #pragma unroll
            for (int nd = 0; nd < 4; nd++) O[nd][r] *= alpha;
        }
        // P -> bf16 -> per-wave LDS strip (swizzled by q-row)
        #pragma unroll
        for (int n = 0; n < 4; n++)
            #pragma unroll
            for (int r = 0; r < 4; r++) {
                const int q = l4 * 4 + r;
                const int byteoff = q * 128 + ((n * 32 + l15 * 2) ^ ((q & 7) << 4));
                *(unsigned short*)((char*)pw + byteoff) = f2bf(S[n][r]);
            }
        const short8 pa0 = *(const short8*)((const char*)pw +
                            l15 * 128 + (((0 + l4) ^ l7) << 4));
        const short8 pa1 = *(const short8*)((const char*)pw +
                            l15 * 128 + (((4 + l4) ^ l7) << 4));
        #pragma unroll
        for (int nd = 0; nd < 4; nd++) {
            const int drow = nd * 16 + l15;    // drow&7 == l7
            const short8 v0 = *(const short8*)((const char*)Vb +
                               drow * 128 + (((0 + l4) ^ l7) << 4));
            const short8 v1 = *(const short8*)((const char*)Vb +
                               drow * 128 + (((4 + l4) ^ l7) << 4));
            O[nd] = __builtin_amdgcn_mfma_f32_16x16x32_bf16(pa0, v0, O[nd], 0, 0, 0);
            O[nd] = __builtin_amdgcn_mfma_f32_16x16x32_bf16(pa1, v1, O[nd], 0, 0, 0);
        }
    };

    const int nt = qtB + 1;
    STAGE(0, 0);
    __syncthreads();                           // drain + barrier: buf0 ready

    for (int jt = 0; jt < nt; ++jt) {
        const int cur = jt & 1;
        if (jt + 1 < nt) STAGE(jt + 1, cur ^ 1);   // next tile in flight
        STRIP(aqB0, aqB1, OB, mB, lB, &Ps[w * 2 + 1][0],
              &Ks[cur][0], &Vts[cur][0], jt == qtB);
        if (jt <= qtA)
            STRIP(aqA0, aqA1, OA, mA, lA, &Ps[w * 2 + 0][0],
                  &Ks[cur][0], &Vts[cur][0], jt == qtA);
        __syncthreads();                       // drains next loads + releases buf
    }

    // normalize + store bf16 in x-layout (b, t, h*64+d) for proj
    #pragma unroll
    for (int r = 0; r < 4; r++) {
        const float invA = 1.0f / lA[r];
        const float invB = 1.0f / lB[r];
        const int tqA = qtA * 64 + w * 16 + l4 * 4 + r;
        const int tqB = qtB * 64 + w * 16 + l4 * 4 + r;
        #pragma unroll
        for (int nd = 0; nd < 4; nd++) {
            const int d = nd * 16 + l15;
            og[((size_t)b * SEQ_T + tqA) * DMODEL + h * 64 + d] = f2bf(OA[nd][r] * invA);
            og[((size_t)b * SEQ_T + tqB) * DMODEL + h * 64 + d] = f2bf(OB[nd][r] * invB);
        }
    }
}

// ---------------------------------------------------------------------------
extern "C" void kernel_launch(void* const* d_in, const int* in_sizes, int n_in,
                              void* d_out, int out_size, void* d_ws, size_t ws_size,
                              hipStream_t stream)
{
    const float* x     = (const float*)d_in[0];
    const float* cosb  = (const float*)d_in[1];
    const float* sinb  = (const float*)d_in[2];
    const float* wqkv  = (const float*)d_in[3];
    const float* wproj = (const float*)d_in[4];
    float* out = (float*)d_out;

    char* ws = (char*)d_ws;                     // 48 MB used
    unsigned short* qbf    = (unsigned short*)(ws);             //  8 MB (B,H,T,D)
    unsigned short* kbf    = (unsigned short*)(ws + (8u<<20));  //  8 MB (B,H,T,D)
    unsigned short* vtbf   = (unsigned short*)(ws + (16u<<20)); //  8 MB (B,H,D,T)
    unsigned short* xbf    = (unsigned short*)(ws + (24u<<20)); //  8 MB (4096,1024)
    unsigned short* wqkvt  = (unsigned short*)(ws + (32u<<20)); //  6 MB (3072,1024)
    unsigned short* wprojt = (unsigned short*)(ws + (38u<<20)); //  2 MB (1024,1024)
    unsigned short* awsbf  = (unsigned short*)(ws + (40u<<20)); //  8 MB (4096,1024)

    k_f32_to_bf16<<<2048, 256, 0, stream>>>(x, xbf, 524288);
    k_transpose_bf16<<<dim3(QKV_N / 32, 1024 / 32), 256, 0, stream>>>(wqkv, wqkvt, QKV_N);
    k_transpose_bf16<<<dim3(1024 / 32, 1024 / 32), 256, 0, stream>>>(wproj, wprojt, 1024);

    k_gemm_qkv<<<dim3(QKV_N / 128, MROWS / 128), 256, 0, stream>>>(
        xbf, wqkvt, cosb, sinb, qbf, kbf, vtbf);
    k_attn<<<512, 256, 0, stream>>>(qbf, kbf, vtbf, awsbf);
    k_gemm_proj<<<dim3(DMODEL / 128, MROWS / 128), 256, 0, stream>>>(awsbf, wprojt, out);
}

// Round 8
// 194.706 us; speedup vs baseline: 4.6378x; 1.0209x over previous
//
#include <hip/hip_runtime.h>
#include <hip/hip_bf16.h>
#include <math.h>

// Problem constants (B=4, T=1024, D_MODEL=1024, H=16, D_HEAD=64)
#define SEQ_T   1024
#define DMODEL  1024
#define NHEAD   16
#define DHEAD   64
#define MROWS   4096            // B*T
#define QKV_N   3072

typedef __attribute__((ext_vector_type(8))) short  short8;   // 8 bf16 = 4 VGPR
typedef __attribute__((ext_vector_type(4))) float  f32x4;    // MFMA C/D frag
typedef __attribute__((ext_vector_type(4))) unsigned short us4;

__device__ __forceinline__ unsigned short f2bf(float f) {
    unsigned u = __float_as_uint(f);
    u += 0x7FFF + ((u >> 16) & 1);          // RNE
    return (unsigned short)(u >> 16);
}
__device__ __forceinline__ float bf2f(unsigned short u) {
    return __uint_as_float((unsigned)u << 16);
}

__device__ __forceinline__ void gload_lds16(const void* g, void* lds) {
    __builtin_amdgcn_global_load_lds(
        (const __attribute__((address_space(1))) void*)g,
        (__attribute__((address_space(3))) void*)lds, 16, 0, 0);
}

// ---------------------------------------------------------------------------
// Fused prologue: one launch for
//   blocks [0,2048)      : x (4096x1024 f32) -> xbf bf16
//   blocks [2048,5120)   : Wqkv (1024x3072) -> wqkvt (3072x1024) bf16
//   blocks [5120,6144)   : Wproj (1024x1024) -> wprojt (1024x1024) bf16
// ---------------------------------------------------------------------------
__global__ __launch_bounds__(256) void k_prep(
    const float* __restrict__ x, const float* __restrict__ wqkv,
    const float* __restrict__ wproj,
    unsigned short* __restrict__ xbf, unsigned short* __restrict__ wqkvt,
    unsigned short* __restrict__ wprojt)
{
    __shared__ float t[32][33];
    const int bid = blockIdx.x;
    const int tid = threadIdx.x;

    if (bid < 2048) {
        // ---- x -> bf16, 8 elems/thread ----
        const int f = bid * 256 + tid;
        const float4 a = ((const float4*)x)[f * 2];
        const float4 b = ((const float4*)x)[f * 2 + 1];
        short8 o;
        o[0] = (short)f2bf(a.x); o[1] = (short)f2bf(a.y);
        o[2] = (short)f2bf(a.z); o[3] = (short)f2bf(a.w);
        o[4] = (short)f2bf(b.x); o[5] = (short)f2bf(b.y);
        o[6] = (short)f2bf(b.z); o[7] = (short)f2bf(b.w);
        *(short8*)&xbf[f * 8] = o;
        return;
    }

    // ---- 32x32 LDS-tiled transpose+convert ----
    const float* in;
    unsigned short* out;
    int N, tt;
    if (bid < 5120) { in = wqkv;  out = wqkvt;  N = QKV_N; tt = bid - 2048; }
    else            { in = wproj; out = wprojt; N = 1024;  tt = bid - 5120; }
    const int ntx = N / 32;
    const int N0 = (tt % ntx) * 32, K0 = (tt / ntx) * 32;

    const int row = tid >> 3, c4 = (tid & 7) * 4;
    const float4 v = *(const float4*)&in[(size_t)(K0 + row) * N + N0 + c4];
    t[c4 + 0][row] = v.x; t[c4 + 1][row] = v.y;
    t[c4 + 2][row] = v.z; t[c4 + 3][row] = v.w;
    __syncthreads();
    us4 o;
    o[0] = f2bf(t[row][c4 + 0]); o[1] = f2bf(t[row][c4 + 1]);
    o[2] = f2bf(t[row][c4 + 2]); o[3] = f2bf(t[row][c4 + 3]);
    *(us4*)&out[(size_t)(N0 + row) * 1024 + K0 + c4] = o;
}

// ---------------------------------------------------------------------------
// Shared MFMA mainloop: C(128x128) += A(128xK) * B^T(128xK), K=1024, BK=32.
// ---------------------------------------------------------------------------
__device__ __forceinline__ void gemm_mainloop(
    const unsigned short* __restrict__ A, const unsigned short* __restrict__ Bt,
    int M0, int N0, unsigned short* As, unsigned short* Bs, f32x4 acc[4][4])
{
    const int tid  = threadIdx.x;
    const int lane = tid & 63, wave = tid >> 6;
    const int wr = wave >> 1, wc = wave & 1;
    const int l15 = lane & 15, l4 = lane >> 4;

    for (int kt = 0; kt < 1024; kt += 32) {
        __syncthreads();                       // waves done reading LDS
        #pragma unroll
        for (int is = 0; is < 2; is++) {
            const int f = is * 256 + tid;      // 0..511
            const int row = f >> 2, seg = f & 3;
            gload_lds16(A  + (size_t)(M0 + row) * 1024 + kt + seg * 8,
                        (char*)As + is * 4096 + wave * 1024);
            gload_lds16(Bt + (size_t)(N0 + row) * 1024 + kt + seg * 8,
                        (char*)Bs + is * 4096 + wave * 1024);
        }
        __syncthreads();                       // drains vmcnt(0)

        short8 af[4], bfr[4];
        #pragma unroll
        for (int m = 0; m < 4; m++)
            af[m] = *(const short8*)((const char*)As +
                     ((wr * 64 + m * 16 + l15) * 64 + l4 * 16));
        #pragma unroll
        for (int n = 0; n < 4; n++)
            bfr[n] = *(const short8*)((const char*)Bs +
                     ((wc * 64 + n * 16 + l15) * 64 + l4 * 16));
        #pragma unroll
        for (int m = 0; m < 4; m++)
            #pragma unroll
            for (int n = 0; n < 4; n++)
                acc[m][n] = __builtin_amdgcn_mfma_f32_16x16x32_bf16(
                    af[m], bfr[n], acc[m][n], 0, 0, 0);
    }
}

// ---------------------------------------------------------------------------
// qkv GEMM + fused RoPE epilogue.
// q,k -> (B,H,T,D) bf16 (roped; q scaled 1/8).  v -> TRANSPOSED (B,H,D,T) bf16.
// C-frag layout (m89): col = lane&15, row = (lane>>4)*4 + reg.
// ---------------------------------------------------------------------------
__global__ __launch_bounds__(256) void k_gemm_qkv(
    const unsigned short* __restrict__ Xbf, const unsigned short* __restrict__ Wt,
    const float* __restrict__ COS, const float* __restrict__ SIN,
    unsigned short* __restrict__ qws, unsigned short* __restrict__ kws,
    unsigned short* __restrict__ vws)
{
    __shared__ __align__(16) unsigned short As[4096];
    __shared__ __align__(16) unsigned short Bs[4096];
    const int M0 = blockIdx.y * 128, N0 = blockIdx.x * 128;

    f32x4 acc[4][4];
    #pragma unroll
    for (int m = 0; m < 4; m++)
        #pragma unroll
        for (int n = 0; n < 4; n++) acc[m][n] = (f32x4)0.f;

    gemm_mainloop(Xbf, Wt, M0, N0, As, Bs, acc);

    const int tid  = threadIdx.x;
    const int lane = tid & 63, wave = tid >> 6;
    const int wr = wave >> 1, wc = wave & 1;
    const int l15 = lane & 15, l4 = lane >> 4;
    const int which = N0 >> 10;                 // uniform per block: 0=q 1=k 2=v

    if (which == 2) {
        // V: store transposed (B,H,D,T); 4 C-regs = 4 consecutive t -> us4.
        #pragma unroll
        for (int m = 0; m < 4; m++) {
            const int rowbase = M0 + wr * 64 + m * 16 + l4 * 4;
            const int bb = rowbase >> 10, t0 = rowbase & 1023;
            #pragma unroll
            for (int n = 0; n < 4; n++) {
                const int cin = (N0 + wc * 64 + n * 16) & 1023;
                const int hh = cin >> 6, d = (cin & 63) + l15;
                us4 o4;
                #pragma unroll
                for (int r = 0; r < 4; r++) o4[r] = f2bf(acc[m][n][r]);
                *(us4*)&vws[(((size_t)bb * NHEAD + hh) * DHEAD + d) * SEQ_T + t0] = o4;
            }
        }
    } else {
        unsigned short* dst = (which == 0) ? qws : kws;
        #pragma unroll
        for (int m = 0; m < 4; m++) {
            #pragma unroll
            for (int n = 0; n < 4; n++) {
                const int cin = (N0 + wc * 64 + n * 16) & 1023;
                const int hh = cin >> 6;
                const int d = (cin & 63) + l15;
                const int rowbase = M0 + wr * 64 + m * 16 + l4 * 4;
                #pragma unroll
                for (int r = 0; r < 4; r++) {
                    const int row = rowbase + r;
                    const int bb = row >> 10, t = row & 1023;
                    const float v = acc[m][n][r];
                    const float p = __shfl_xor(v, 1, 64);
                    const float c = COS[t * 64 + d];
                    const float s = SIN[t * 64 + d];
                    float o = (lane & 1) ? fmaf(v, c, p * s) : fmaf(v, c, -(p * s));
                    if (which == 0) o *= 0.125f;     // 1/sqrt(64)
                    dst[(((size_t)bb * NHEAD + hh) * SEQ_T + t) * DHEAD + d] = f2bf(o);
                }
            }
        }
    }
}

// ---------------------------------------------------------------------------
// proj GEMM -> fp32 out (4096x1024)
// ---------------------------------------------------------------------------
__global__ __launch_bounds__(256) void k_gemm_proj(
    const unsigned short* __restrict__ Abf, const unsigned short* __restrict__ Wt,
    float* __restrict__ C)
{
    __shared__ __align__(16) unsigned short As[4096];
    __shared__ __align__(16) unsigned short Bs[4096];
    const int M0 = blockIdx.y * 128, N0 = blockIdx.x * 128;

    f32x4 acc[4][4];
    #pragma unroll
    for (int m = 0; m < 4; m++)
        #pragma unroll
        for (int n = 0; n < 4; n++) acc[m][n] = (f32x4)0.f;

    gemm_mainloop(Abf, Wt, M0, N0, As, Bs, acc);

    const int tid  = threadIdx.x;
    const int lane = tid & 63, wave = tid >> 6;
    const int wr = wave >> 1, wc = wave & 1;
    const int l15 = lane & 15, l4 = lane >> 4;

    #pragma unroll
    for (int m = 0; m < 4; m++) {
        #pragma unroll
        for (int n = 0; n < 4; n++) {
            const int col = N0 + wc * 64 + n * 16 + l15;
            const int rowbase = M0 + wr * 64 + m * 16 + l4 * 4;
            #pragma unroll
            for (int r = 0; r < 4; r++)
                C[(size_t)(rowbase + r) * 1024 + col] = acc[m][n][r];
        }
    }
}

// ---------------------------------------------------------------------------
// MFMA flash attention, causal-pair balanced + 2-phase pipelined + setprio.
// Block = (pair, h, b) flattened 1D (XCD-swizzled); q-tiles pair & 15-pair.
// ---------------------------------------------------------------------------
__global__ __launch_bounds__(256) void k_attn(
    const unsigned short* __restrict__ qg, const unsigned short* __restrict__ kg,
    const unsigned short* __restrict__ vtg, unsigned short* __restrict__ og)
{
    __shared__ __align__(16) unsigned short Ks[2][4096];   // [buf][64 krows x 64 d] swz
    __shared__ __align__(16) unsigned short Vts[2][4096];  // [buf][64 drows x 64 t] swz
    __shared__ __align__(16) unsigned short Ps[8][1024];   // [wave*2+strip][16q x 64k] swz

    const int tid  = threadIdx.x;
    const int lane = tid & 63, w = tid >> 6;
    const int l15 = lane & 15, l4 = lane >> 4, l7 = lane & 7;

    // XCD swizzle: 512 blocks, 8 XCDs -> each XCD gets 8 full (b,h) groups.
    const int logical = (blockIdx.x & 7) * 64 + (blockIdx.x >> 3);
    const int bh = logical >> 3, pair = logical & 7;
    const int b = bh >> 4, h = bh & 15;
    const int qtA = pair, qtB = 15 - pair;

    const size_t hb     = (size_t)b * NHEAD + h;
    const size_t qkbase = hb * SEQ_T * DHEAD;   // q,k: (T,D)
    const size_t vtbase = hb * DHEAD * SEQ_T;   // vt:  (D,T)

    const int qrowA = qtA * 64 + w * 16 + l15;
    const int qrowB = qtB * 64 + w * 16 + l15;
    const short8 aqA0 = *(const short8*)&qg[qkbase + (size_t)qrowA * 64 +      l4 * 8];
    const short8 aqA1 = *(const short8*)&qg[qkbase + (size_t)qrowA * 64 + 32 + l4 * 8];
    const short8 aqB0 = *(const short8*)&qg[qkbase + (size_t)qrowB * 64 +      l4 * 8];
    const short8 aqB1 = *(const short8*)&qg[qkbase + (size_t)qrowB * 64 + 32 + l4 * 8];

    f32x4 OA[4], OB[4];
    float mA[4], lA[4], mB[4], lB[4];
    #pragma unroll
    for (int nd = 0; nd < 4; nd++) { OA[nd] = (f32x4)0.f; OB[nd] = (f32x4)0.f; }
    #pragma unroll
    for (int r = 0; r < 4; r++) {
        mA[r] = -INFINITY; lA[r] = 0.f; mB[r] = -INFINITY; lB[r] = 0.f;
    }

    auto STAGE = [&](int jt, int bi) {
        #pragma unroll
        for (int i = 0; i < 2; i++) {
            const int c = i * 256 + tid;       // 16B-chunk id
            const int row = c >> 3, ps = c & 7;
            const int ls = ps ^ (row & 7);     // inverse-swizzled source seg
            gload_lds16(kg + qkbase + (size_t)(jt * 64 + row) * 64 + ls * 8,
                        (char*)&Ks[bi][0] + i * 4096 + w * 1024);
            gload_lds16(vtg + vtbase + (size_t)row * 1024 + jt * 64 + ls * 8,
                        (char*)&Vts[bi][0] + i * 4096 + w * 1024);
        }
    };

    auto STRIP = [&](const short8& aq0, const short8& aq1, f32x4* O,
                     float* m_i, float* l_i, unsigned short* pw,
                     const unsigned short* Kb, const unsigned short* Vb,
                     bool maskdiag) {
        f32x4 S[4];
        #pragma unroll
        for (int n = 0; n < 4; n++) S[n] = (f32x4)0.f;
        __builtin_amdgcn_s_setprio(1);
        #pragma unroll
        for (int n = 0; n < 4; n++) {
            const int krow = n * 16 + l15;     // krow&7 == l7
            const short8 bk0 = *(const short8*)((const char*)Kb +
                                krow * 128 + (((0 + l4) ^ l7) << 4));
            const short8 bk1 = *(const short8*)((const char*)Kb +
                                krow * 128 + (((4 + l4) ^ l7) << 4));
            S[n] = __builtin_amdgcn_mfma_f32_16x16x32_bf16(aq0, bk0, S[n], 0, 0, 0);
            S[n] = __builtin_amdgcn_mfma_f32_16x16x32_bf16(aq1, bk1, S[n], 0, 0, 0);
        }
        __builtin_amdgcn_s_setprio(0);
        if (maskdiag) {
            #pragma unroll
            for (int n = 0; n < 4; n++)
                #pragma unroll
                for (int r = 0; r < 4; r++)
                    if (n * 16 + l15 > w * 16 + l4 * 4 + r) S[n][r] = -INFINITY;
        }
        #pragma unroll
        for (int r = 0; r < 4; r++) {
            float mx = fmaxf(fmaxf(S[0][r], S[1][r]), fmaxf(S[2][r], S[3][r]));
            #pragma unroll
            for (int off = 1; off < 16; off <<= 1)
                mx = fmaxf(mx, __shfl_xor(mx, off, 64));
            const float mnew  = fmaxf(m_i[r], mx);
            const float alpha = __expf(m_i[r] - mnew);   // 0 on first tile
            m_i[r] = mnew;
            float rs = 0.f;
            #pragma unroll
            for (int n = 0; n < 4; n++) {
                const float p = __expf(S[n][r] - mnew);
                S[n][r] = p;
                rs += p;
            }
            #pragma unroll
            for (int off = 1; off < 16; off <<= 1)
                rs += __shfl_xor(rs, off, 64);
            l_i[r] = l_i[r] * alpha + rs;
            #pragma unroll
            for (int nd = 0; nd < 4; nd++) O[nd][r] *= alpha;
        }
        // P -> bf16 -> per-wave LDS strip (swizzled by q-row)
        #pragma unroll
        for (int n = 0; n < 4; n++)
            #pragma unroll
            for (int r = 0; r < 4; r++) {
                const int q = l4 * 4 + r;
                const int byteoff = q * 128 + ((n * 32 + l15 * 2) ^ ((q & 7) << 4));
                *(unsigned short*)((char*)pw + byteoff) = f2bf(S[n][r]);
            }
        const short8 pa0 = *(const short8*)((const char*)pw +
                            l15 * 128 + (((0 + l4) ^ l7) << 4));
        const short8 pa1 = *(const short8*)((const char*)pw +
                            l15 * 128 + (((4 + l4) ^ l7) << 4));
        __builtin_amdgcn_s_setprio(1);
        #pragma unroll
        for (int nd = 0; nd < 4; nd++) {
            const int drow = nd * 16 + l15;    // drow&7 == l7
            const short8 v0 = *(const short8*)((const char*)Vb +
                               drow * 128 + (((0 + l4) ^ l7) << 4));
            const short8 v1 = *(const short8*)((const char*)Vb +
                               drow * 128 + (((4 + l4) ^ l7) << 4));
            O[nd] = __builtin_amdgcn_mfma_f32_16x16x32_bf16(pa0, v0, O[nd], 0, 0, 0);
            O[nd] = __builtin_amdgcn_mfma_f32_16x16x32_bf16(pa1, v1, O[nd], 0, 0, 0);
        }
        __builtin_amdgcn_s_setprio(0);
    };

    const int nt = qtB + 1;
    STAGE(0, 0);
    __syncthreads();                           // drain + barrier: buf0 ready

    for (int jt = 0; jt < nt; ++jt) {
        const int cur = jt & 1;
        if (jt + 1 < nt) STAGE(jt + 1, cur ^ 1);   // next tile in flight
        STRIP(aqB0, aqB1, OB, mB, lB, &Ps[w * 2 + 1][0],
              &Ks[cur][0], &Vts[cur][0], jt == qtB);
        if (jt <= qtA)
            STRIP(aqA0, aqA1, OA, mA, lA, &Ps[w * 2 + 0][0],
                  &Ks[cur][0], &Vts[cur][0], jt == qtA);
        __syncthreads();                       // drains next loads + releases buf
    }

    // normalize + store bf16 in x-layout (b, t, h*64+d) for proj
    #pragma unroll
    for (int r = 0; r < 4; r++) {
        const float invA = 1.0f / lA[r];
        const float invB = 1.0f / lB[r];
        const int tqA = qtA * 64 + w * 16 + l4 * 4 + r;
        const int tqB = qtB * 64 + w * 16 + l4 * 4 + r;
        #pragma unroll
        for (int nd = 0; nd < 4; nd++) {
            const int d = nd * 16 + l15;
            og[((size_t)b * SEQ_T + tqA) * DMODEL + h * 64 + d] = f2bf(OA[nd][r] * invA);
            og[((size_t)b * SEQ_T + tqB) * DMODEL + h * 64 + d] = f2bf(OB[nd][r] * invB);
        }
    }
}

// ---------------------------------------------------------------------------
extern "C" void kernel_launch(void* const* d_in, const int* in_sizes, int n_in,
                              void* d_out, int out_size, void* d_ws, size_t ws_size,
                              hipStream_t stream)
{
    const float* x     = (const float*)d_in[0];
    const float* cosb  = (const float*)d_in[1];
    const float* sinb  = (const float*)d_in[2];
    const float* wqkv  = (const float*)d_in[3];
    const float* wproj = (const float*)d_in[4];
    float* out = (float*)d_out;

    char* ws = (char*)d_ws;                     // 48 MB used
    unsigned short* qbf    = (unsigned short*)(ws);             //  8 MB (B,H,T,D)
    unsigned short* kbf    = (unsigned short*)(ws + (8u<<20));  //  8 MB (B,H,T,D)
    unsigned short* vtbf   = (unsigned short*)(ws + (16u<<20)); //  8 MB (B,H,D,T)
    unsigned short* xbf    = (unsigned short*)(ws + (24u<<20)); //  8 MB (4096,1024)
    unsigned short* wqkvt  = (unsigned short*)(ws + (32u<<20)); //  6 MB (3072,1024)
    unsigned short* wprojt = (unsigned short*)(ws + (38u<<20)); //  2 MB (1024,1024)
    unsigned short* awsbf  = (unsigned short*)(ws + (40u<<20)); //  8 MB (4096,1024)

    k_prep<<<6144, 256, 0, stream>>>(x, wqkv, wproj, xbf, wqkvt, wprojt);
    k_gemm_qkv<<<dim3(QKV_N / 128, MROWS / 128), 256, 0, stream>>>(
        xbf, wqkvt, cosb, sinb, qbf, kbf, vtbf);
    k_attn<<<512, 256, 0, stream>>>(qbf, kbf, vtbf, awsbf);
    k_gemm_proj<<<dim3(DMODEL / 128, MROWS / 128), 256, 0, stream>>>(awsbf, wprojt, out);
}